// Round 11
// baseline (283.893 us; speedup 1.0000x reference)
//
#include <hip/hip_runtime.h>

#define NN 500
#define BB 32
#define TT 12
#define EMB 10

typedef float f2v __attribute__((ext_vector_type(2)));
typedef float f4v __attribute__((ext_vector_type(4)));

#define PKFMA(A, W, C) asm("v_pk_fma_f32 %0, %1, %2, %0" : "+v"(A) : "v"(W), "v"(C))
#define SHUF2(V, a, b) __builtin_shufflevector((V), (V), (a), (b))

// ---------------- K1: S = softmax(relu(E E^T) with diag=stay), rows ----------------
__global__ __launch_bounds__(256) void k_softmaxS(const float* __restrict__ E,
                                                  const int* __restrict__ stay,
                                                  float* __restrict__ S) {
    const int i = blockIdx.x;
    const int tid = threadIdx.x;
    __shared__ float row[NN];
    __shared__ float red[256];
    float ei[EMB];
#pragma unroll
    for (int d = 0; d < EMB; ++d) ei[d] = E[i * EMB + d];
    const float stayf = (float)stay[0];

    float lmax = -1e30f;
    for (int j = tid; j < NN; j += 256) {
        float acc = 0.f;
#pragma unroll
        for (int d = 0; d < EMB; ++d) acc += ei[d] * E[j * EMB + d];
        float v = acc > 0.f ? acc : 0.f;
        if (j == i) v = stayf;
        row[j] = v;
        lmax = fmaxf(lmax, v);
    }
    red[tid] = lmax;
    __syncthreads();
    for (int s = 128; s > 0; s >>= 1) {
        if (tid < s) red[tid] = fmaxf(red[tid], red[tid + s]);
        __syncthreads();
    }
    const float rmax = red[0];
    __syncthreads();

    float lsum = 0.f;
    for (int j = tid; j < NN; j += 256) {
        float e = __expf(row[j] - rmax);
        row[j] = e;
        lsum += e;
    }
    red[tid] = lsum;
    __syncthreads();
    for (int s = 128; s > 0; s >>= 1) {
        if (tid < s) red[tid] += red[tid + s];
        __syncthreads();
    }
    const float inv = 1.0f / red[0];
    for (int j = tid; j < NN; j += 256) S[i * NN + j] = row[j] * inv;
}

// ---------------- K2/K3: y[b,n] = sum_m S[n,m] * xin[b,m] (wave per row) ----------------
__global__ __launch_bounds__(256) void k_matvecS(const float* __restrict__ S,
                                                 const float* __restrict__ xin,
                                                 float* __restrict__ yout) {
    const int b = blockIdx.y;
    const int w = threadIdx.x >> 6;
    const int lane = threadIdx.x & 63;
    const int n = blockIdx.x * 4 + w;
    const float* xb = xin + b * NN;
    const float* Sr = S + n * NN;
    float acc = 0.f;
    for (int m = lane; m < NN; m += 64) acc += Sr[m] * xb[m];
#pragma unroll
    for (int off = 32; off > 0; off >>= 1) acc += __shfl_down(acc, off, 64);
    if (lane == 0) yout[b * NN + n] = acc;
}

// ---------------- K4: per-node small weights from embeddings ----------------
__global__ __launch_bounds__(256) void k_smallpre(const float* __restrict__ E,
                                                  const float* __restrict__ wp,
                                                  const float* __restrict__ bp,
                                                  const float* __restrict__ wwsp,
                                                  const float* __restrict__ wwtp,
                                                  float* __restrict__ W,
                                                  float* __restrict__ biasN,
                                                  float* __restrict__ wws,
                                                  float* __restrict__ wwt) {
    const int n = blockIdx.x;
    const int tid = threadIdx.x;
    __shared__ float e[EMB];
    if (tid < EMB) e[tid] = E[n * EMB + tid];
    __syncthreads();
    if (tid < 144) {
        float acc = 0.f;
#pragma unroll
        for (int d = 0; d < EMB; ++d) acc += e[d] * wp[d * 144 + tid];
        W[n * 144 + tid] = acc;
    } else if (tid < 208) {
        const int o = tid - 144;
        float acc = 0.f;
#pragma unroll
        for (int d = 0; d < EMB; ++d) acc += e[d] * bp[d * 64 + o];
        biasN[n * 64 + o] = acc;
    } else if (tid < 216) {
        const int o = tid - 208;
        float acc = 0.f;
#pragma unroll
        for (int d = 0; d < EMB; ++d) acc += e[d] * wwsp[d * 8 + o];
        wws[n * 8 + o] = acc;
    } else if (tid < 224) {
        const int o = tid - 216;
        float acc = 0.f;
#pragma unroll
        for (int d = 0; d < EMB; ++d) acc += e[d] * wwtp[d * 8 + o];
        wwt[n * 8 + o] = acc;
    }
}

// ---------------- K5: M[b,n] = mean_f xws, wsum[b,n] = sum_t xw[b,t,n]*T[t] ----------------
__global__ __launch_bounds__(128) void k_Mwsum(const float* __restrict__ xwin,
                                               const float* __restrict__ S,
                                               const int* __restrict__ bidx,
                                               const int* __restrict__ jumpc,
                                               const float* __restrict__ Tp,
                                               float* __restrict__ M,
                                               float* __restrict__ wsum) {
    const int b = blockIdx.y;
    const int n0 = blockIdx.x * 125;
    const int tid = threadIdx.x;
    __shared__ float xsf[NN];
    __shared__ float Tl[TT];
    const int t0 = bidx[0], t1 = bidx[1], t2 = bidx[2];
    if (tid < TT) Tl[tid] = Tp[tid];
    const float* xb = xwin + (size_t)b * TT * NN;
    for (int m = tid; m < NN; m += 128)
        xsf[m] = xb[t0 * NN + m] + xb[t1 * NN + m] + xb[t2 * NN + m];
    __syncthreads();
    if (tid < 125) {
        const int n = n0 + tid;
        float ws_ = 0.f;
#pragma unroll
        for (int t = 0; t < TT; ++t) ws_ += xb[t * NN + n] * Tl[t];
        const float jc = (float)jumpc[0];
        const float jterm = jc * (2.f * xb[t0 * NN + n] + xb[t1 * NN + n]);
        float acc = 0.f;
        for (int m = 0; m < NN; ++m) acc += xsf[m] * S[m * NN + n];
        M[b * NN + n] = (acc + jterm) * (1.f / 3.f);
        wsum[b * NN + n] = ws_;
    }
}

// ---------------- K_wpack: duplicate-pair pack -> wpack2[t][kh][kw][c8][2] ----------------
__global__ __launch_bounds__(256) void k_wpack(const float* __restrict__ wm,
                                               const float* __restrict__ wx,
                                               float* __restrict__ wpack2) {
    const int i = blockIdx.x * 256 + threadIdx.x;
    if (i >= TT * 3 * 3 * 8 * 2) return;
    int j = i >> 1;
    const int c = j & 7; j >>= 3;
    const int kw = j % 3; j /= 3;
    const int kh = j % 3;
    const int t = j / 3;
    const float v = (c < 4) ? wm[((c * TT + t) * 3 + kh) * 3 + kw]
                            : wx[(((c - 4) * TT + t) * 3 + kh) * 3 + kw];
    wpack2[i] = v;
}

// ---------------- K6: fused dual conv — LDS dbuf (R4 schedule) + pk-FMA body (R10 math) --------
// Block: 2 output rows (r0, r0+1), 256 thr = 2 row-groups x 128 col-threads (4 cols each).
// LDS stages 4 input rows r0-1..r0+2, linear [4*500] floats, double-buffered.
// Edges (col 4tx-1, 4tx+4) prefetched from global one t ahead (L1-hot rows).
__global__ __launch_bounds__(256, 4) void k_conv(const float* __restrict__ MPG,
                                                 const float* __restrict__ wpack2,
                                                 const float* __restrict__ bmv,
                                                 const float* __restrict__ bxv,
                                                 const float* __restrict__ zrow,
                                                 float* __restrict__ partials) {
    const int b = blockIdx.y;
    const int r0 = blockIdx.x * 2;
    const int tid = threadIdx.x;
    const int ry = __builtin_amdgcn_readfirstlane(tid >> 7);  // wave-uniform row group
    const int tx = tid & 127;
    const int lane = tid & 63;
    const bool active = (tx < 125);

    __shared__ float buf[2][2048];
    __shared__ float wred[4][8];

    const float* base_b = MPG + (size_t)b * (TT * NN * NN);

    // --- staging: 500 float4 per tile; thread handles f4 index f = tid, tid+256 ---
    const float* sp[2];
    int sadv[2];
    int sdst[2];
#pragma unroll
    for (int k = 0; k < 2; ++k) {
        const int f = tid + k * 256;
        const int row = f / 125;           // 0..4 (f up to 511)
        const int col = (f - row * 125) * 4;
        const int grow = r0 - 1 + row;
        const bool ok = (f < 500) && (grow >= 0) && (grow < NN);
        sp[k] = ok ? base_b + (size_t)grow * NN + col : zrow + col;
        sadv[k] = ok ? NN * NN : 0;
        sdst[k] = f * 4;                   // float offset in buf (max 2044)
    }

    // --- edge loads: rows R-1+kh, R = r0+ry ---
    const float* rp[3];
    int radv[3];
#pragma unroll
    for (int kh = 0; kh < 3; ++kh) {
        const int gr = r0 + ry - 1 + kh;
        const bool ok = (gr >= 0) && (gr < NN);
        rp[kh] = ok ? base_b + (size_t)gr * NN : zrow;
        radv[kh] = ok ? NN * NN : 0;
    }
    const int voffL = (active && tx > 0) ? tx * 16 - 4 : 0;
    const int voffR = (active && tx < 124) ? tx * 16 + 16 : 0;
    const float mL = (active && tx > 0) ? 1.f : 0.f;
    const float mR = (active && tx < 124) ? 1.f : 0.f;

    f2v acc[8][2];
#pragma unroll
    for (int c = 0; c < 8; ++c) {
        const float bv = (c < 4) ? bmv[c] : bxv[c - 4];
        acc[c][0] = f2v{bv, bv};
        acc[c][1] = f2v{bv, bv};
    }

    float4 p0, p1;
    float eL[3], eR[3], nL[3], nR[3];

    // prologue: stage t=0
    p0 = *reinterpret_cast<const float4*>(sp[0]);
    p1 = *reinterpret_cast<const float4*>(sp[1]);
#pragma unroll
    for (int kh = 0; kh < 3; ++kh) {
        eL[kh] = *reinterpret_cast<const float*>(reinterpret_cast<const char*>(rp[kh]) + voffL);
        eR[kh] = *reinterpret_cast<const float*>(reinterpret_cast<const char*>(rp[kh]) + voffR);
        rp[kh] += radv[kh];
    }
    sp[0] += sadv[0]; sp[1] += sadv[1];
    *reinterpret_cast<float4*>(&buf[0][sdst[0]]) = p0;
    *reinterpret_cast<float4*>(&buf[0][sdst[1]]) = p1;
    __syncthreads();

#pragma unroll 1
    for (int t = 0; t < TT; ++t) {
        const int pb = t & 1;
        const bool pf = (t + 1) < TT;
        // issue next-tile loads early (fly under this tile's compute)
        if (pf) {
            p0 = *reinterpret_cast<const float4*>(sp[0]);
            p1 = *reinterpret_cast<const float4*>(sp[1]);
#pragma unroll
            for (int kh = 0; kh < 3; ++kh) {
                nL[kh] = *reinterpret_cast<const float*>(reinterpret_cast<const char*>(rp[kh]) + voffL);
                nR[kh] = *reinterpret_cast<const float*>(reinterpret_cast<const char*>(rp[kh]) + voffR);
                rp[kh] += radv[kh];
            }
            sp[0] += sadv[0]; sp[1] += sadv[1];
        }

        // compute tile t from buf[pb] + edge regs, pk-FMA
        const float* wb = wpack2 + t * 144;
        const float* lb = &buf[pb][0];
#pragma unroll
        for (int kh = 0; kh < 3; ++kh) {
            const f4v q = *reinterpret_cast<const f4v*>(lb + ((ry + kh) * NN + tx * 4));
            const f2v P0 = SHUF2(q, 0, 1);
            const f2v P1 = SHUF2(q, 2, 3);
            const f2v Mw = SHUF2(q, 1, 2);
            const f2v Lw = f2v{eL[kh] * mL, q.x};
            const f2v Rw = f2v{q.w, eR[kh] * mR};
            const float* wk = wb + kh * 48;
#pragma unroll
            for (int kw = 0; kw < 3; ++kw) {
                const f4v w01 = *reinterpret_cast<const f4v*>(wk + kw * 16);
                const f4v w23 = *reinterpret_cast<const f4v*>(wk + kw * 16 + 4);
                const f4v w45 = *reinterpret_cast<const f4v*>(wk + kw * 16 + 8);
                const f4v w67 = *reinterpret_cast<const f4v*>(wk + kw * 16 + 12);
                const f2v wc[8] = {SHUF2(w01, 0, 1), SHUF2(w01, 2, 3),
                                   SHUF2(w23, 0, 1), SHUF2(w23, 2, 3),
                                   SHUF2(w45, 0, 1), SHUF2(w45, 2, 3),
                                   SHUF2(w67, 0, 1), SHUF2(w67, 2, 3)};
                const f2v A0 = (kw == 0) ? Lw : ((kw == 1) ? P0 : Mw);
                const f2v A1 = (kw == 0) ? Mw : ((kw == 1) ? P1 : Rw);
#pragma unroll
                for (int c = 0; c < 8; ++c) {
                    PKFMA(acc[c][0], A0, wc[c]);
                    PKFMA(acc[c][1], A1, wc[c]);
                }
            }
        }

        // write next tile into the other buffer (T14 write-late), then barrier
        if (pf) {
            *reinterpret_cast<float4*>(&buf[pb ^ 1][sdst[0]]) = p0;
            *reinterpret_cast<float4*>(&buf[pb ^ 1][sdst[1]]) = p1;
        }
        __syncthreads();
#pragma unroll
        for (int kh = 0; kh < 3; ++kh) { eL[kh] = nL[kh]; eR[kh] = nR[kh]; }
    }

    // relu + per-thread reduce (4 cols)
    const float mk = active ? 1.f : 0.f;
    float vals[8];
#pragma unroll
    for (int c = 0; c < 4; ++c) {
        float s0 = 0.f, m0 = 0.f;
#pragma unroll
        for (int p = 0; p < 2; ++p) {
            s0 += fmaxf(acc[c][p].x, 0.f) + fmaxf(acc[c][p].y, 0.f);
            m0 = fmaxf(m0, fmaxf(fmaxf(acc[c + 4][p].x, 0.f), fmaxf(acc[c + 4][p].y, 0.f)));
        }
        vals[c] = s0 * mk;
        vals[c + 4] = m0 * mk;
    }

    // wave butterfly reduce
#pragma unroll
    for (int off = 32; off > 0; off >>= 1) {
#pragma unroll
        for (int c = 0; c < 4; ++c) vals[c] += __shfl_xor(vals[c], off, 64);
#pragma unroll
        for (int c = 4; c < 8; ++c) vals[c] = fmaxf(vals[c], __shfl_xor(vals[c], off, 64));
    }
    const int wv = tid >> 6;
    if (lane == 0) {
#pragma unroll
        for (int c = 0; c < 8; ++c) wred[wv][c] = vals[c];
    }
    __syncthreads();
    if (tid < 8) {
        const float a0 = wred[0][tid], a1 = wred[1][tid], a2 = wred[2][tid], a3 = wred[3][tid];
        const float r = (tid < 4) ? (a0 + a1 + a2 + a3) : fmaxf(fmaxf(a0, a1), fmaxf(a2, a3));
        partials[((size_t)b * 250 + blockIdx.x) * 8 + tid] = r;
    }
}

// ---------------- K7: reduce partials -> topo[b][8] ----------------
__global__ __launch_bounds__(256) void k_topo(const float* __restrict__ partials,
                                              float* __restrict__ topo) {
    const int b = blockIdx.x;
    const int tid = threadIdx.x;
    const int c = tid & 7;
    const int g = tid >> 3;  // 32 groups
    float vs = 0.f, vm = 0.f;
    for (int rp = g; rp < 250; rp += 32) {
        const float v = partials[((size_t)b * 250 + rp) * 8 + c];
        vs += v;
        vm = fmaxf(vm, v);
    }
    __shared__ float red[256];
    red[tid] = (c < 4) ? vs : vm;
    __syncthreads();
    for (int s = 16; s > 0; s >>= 1) {
        if (g < s) {
            const float a = red[tid];
            const float bv = red[tid + s * 8];
            red[tid] = (c < 4) ? (a + bv) : fmaxf(a, bv);
        }
        __syncthreads();
    }
    if (tid < 8) topo[b * 8 + tid] = (tid < 4) ? red[tid] * (1.f / (NN * (float)NN)) : red[tid];
}

// ---------------- K8: assemble output ----------------
__global__ __launch_bounds__(64) void k_out(const float* __restrict__ x,
                                            const float* __restrict__ y1,
                                            const float* __restrict__ y2,
                                            const float* __restrict__ W,
                                            const float* __restrict__ biasN,
                                            const float* __restrict__ wws,
                                            const float* __restrict__ wwt,
                                            const float* __restrict__ M,
                                            const float* __restrict__ wsum,
                                            const float* __restrict__ topo,
                                            float* __restrict__ out) {
    const int bn = blockIdx.x;
    const int b = bn / NN;
    const int n = bn - b * NN;
    const int o = threadIdx.x;
    float val;
    if (o < 48) {
        val = x[bn] * W[n * 144 + o] + y1[bn] * W[n * 144 + 48 + o] + y2[bn] * W[n * 144 + 96 + o];
    } else if (o < 56) {
        const int oo = o - 48;
        val = M[bn] * wws[n * 8 + oo] * topo[b * 8 + oo];
    } else {
        const int oo = o - 56;
        val = wsum[bn] * wwt[n * 8 + oo];
    }
    out[(size_t)bn * 64 + o] = val + biasN[n * 64 + o];
}

extern "C" void kernel_launch(void* const* d_in, const int* in_sizes, int n_in,
                              void* d_out, int out_size, void* d_ws, size_t ws_size,
                              hipStream_t stream) {
    const float* x    = (const float*)d_in[0];
    const float* xw   = (const float*)d_in[1];
    const float* E    = (const float*)d_in[2];
    const float* MPG  = (const float*)d_in[4];
    const int*   bidx = (const int*)d_in[5];
    const int*   stay = (const int*)d_in[7];
    const int*   jump = (const int*)d_in[8];
    const float* wp   = (const float*)d_in[9];
    const float* wwsp = (const float*)d_in[10];
    const float* wwtp = (const float*)d_in[11];
    const float* bp   = (const float*)d_in[12];
    const float* Tp   = (const float*)d_in[13];
    const float* cmw  = (const float*)d_in[14];
    const float* cmb  = (const float*)d_in[15];
    const float* cxw  = (const float*)d_in[16];
    const float* cxb  = (const float*)d_in[17];
    float* out = (float*)d_out;

    float* w = (float*)d_ws;
    float* S     = w;               // 250000
    float* y1    = S + 250000;      // 16000
    float* y2    = y1 + 16000;      // 16000
    float* W     = y2 + 16000;      // 72000
    float* biasN = W + 72000;       // 32000
    float* wws   = biasN + 32000;   // 4000
    float* wwt   = wws + 4000;      // 4000
    float* M     = wwt + 4000;      // 16000
    float* wsum  = M + 16000;       // 16000
    float* parts = wsum + 16000;    // 64000
    float* topo  = parts + 64000;   // 256
    float* zrow  = topo + 256;      // 640 floats zero page
    float* wpck  = zrow + 640;      // 1728 duplicated weight pairs

    hipMemsetAsync(zrow, 0, 640 * sizeof(float), stream);
    k_wpack<<<7, 256, 0, stream>>>(cmw, cxw, wpck);
    k_softmaxS<<<NN, 256, 0, stream>>>(E, stay, S);
    k_matvecS<<<dim3(125, BB), 256, 0, stream>>>(S, x, y1);
    k_matvecS<<<dim3(125, BB), 256, 0, stream>>>(S, y1, y2);
    k_smallpre<<<NN, 256, 0, stream>>>(E, wp, bp, wwsp, wwtp, W, biasN, wws, wwt);
    k_Mwsum<<<dim3(4, BB), 128, 0, stream>>>(xw, S, bidx, jump, Tp, M, wsum);
    k_conv<<<dim3(250, BB), 256, 0, stream>>>(MPG, wpck, cmb, cxb, zrow, parts);
    k_topo<<<BB, 256, 0, stream>>>(parts, topo);
    k_out<<<BB * NN, 64, 0, stream>>>(x, y1, y2, W, biasN, wws, wwt, M, wsum, topo, out);
}

// Round 12
// 151.398 us; speedup vs baseline: 1.8751x; 1.8751x over previous
//
#include <hip/hip_runtime.h>

#define NN 500
#define BB 32
#define TT 12
#define EMB 10

typedef short bf16x8 __attribute__((ext_vector_type(8)));
typedef float f32x16 __attribute__((ext_vector_type(16)));

__device__ __forceinline__ unsigned short f2bf(float x) {
    unsigned int u = __float_as_uint(x);
    u = (u + 0x7fffu + ((u >> 16) & 1u)) >> 16;   // round-to-nearest-even
    return (unsigned short)u;
}

// ---------------- K1: S = softmax(relu(E E^T) with diag=stay), rows ----------------
__global__ __launch_bounds__(256) void k_softmaxS(const float* __restrict__ E,
                                                  const int* __restrict__ stay,
                                                  float* __restrict__ S) {
    const int i = blockIdx.x;
    const int tid = threadIdx.x;
    __shared__ float row[NN];
    __shared__ float red[256];
    float ei[EMB];
#pragma unroll
    for (int d = 0; d < EMB; ++d) ei[d] = E[i * EMB + d];
    const float stayf = (float)stay[0];

    float lmax = -1e30f;
    for (int j = tid; j < NN; j += 256) {
        float acc = 0.f;
#pragma unroll
        for (int d = 0; d < EMB; ++d) acc += ei[d] * E[j * EMB + d];
        float v = acc > 0.f ? acc : 0.f;
        if (j == i) v = stayf;
        row[j] = v;
        lmax = fmaxf(lmax, v);
    }
    red[tid] = lmax;
    __syncthreads();
    for (int s = 128; s > 0; s >>= 1) {
        if (tid < s) red[tid] = fmaxf(red[tid], red[tid + s]);
        __syncthreads();
    }
    const float rmax = red[0];
    __syncthreads();

    float lsum = 0.f;
    for (int j = tid; j < NN; j += 256) {
        float e = __expf(row[j] - rmax);
        row[j] = e;
        lsum += e;
    }
    red[tid] = lsum;
    __syncthreads();
    for (int s = 128; s > 0; s >>= 1) {
        if (tid < s) red[tid] += red[tid + s];
        __syncthreads();
    }
    const float inv = 1.0f / red[0];
    for (int j = tid; j < NN; j += 256) S[i * NN + j] = row[j] * inv;
}

// ---------------- K2/K3: y[b,n] = sum_m S[n,m] * xin[b,m] (wave per row) ----------------
__global__ __launch_bounds__(256) void k_matvecS(const float* __restrict__ S,
                                                 const float* __restrict__ xin,
                                                 float* __restrict__ yout) {
    const int b = blockIdx.y;
    const int w = threadIdx.x >> 6;
    const int lane = threadIdx.x & 63;
    const int n = blockIdx.x * 4 + w;
    const float* xb = xin + b * NN;
    const float* Sr = S + n * NN;
    float acc = 0.f;
    for (int m = lane; m < NN; m += 64) acc += Sr[m] * xb[m];
#pragma unroll
    for (int off = 32; off > 0; off >>= 1) acc += __shfl_down(acc, off, 64);
    if (lane == 0) yout[b * NN + n] = acc;
}

// ---------------- K4: per-node small weights from embeddings ----------------
__global__ __launch_bounds__(256) void k_smallpre(const float* __restrict__ E,
                                                  const float* __restrict__ wp,
                                                  const float* __restrict__ bp,
                                                  const float* __restrict__ wwsp,
                                                  const float* __restrict__ wwtp,
                                                  float* __restrict__ W,
                                                  float* __restrict__ biasN,
                                                  float* __restrict__ wws,
                                                  float* __restrict__ wwt) {
    const int n = blockIdx.x;
    const int tid = threadIdx.x;
    __shared__ float e[EMB];
    if (tid < EMB) e[tid] = E[n * EMB + tid];
    __syncthreads();
    if (tid < 144) {
        float acc = 0.f;
#pragma unroll
        for (int d = 0; d < EMB; ++d) acc += e[d] * wp[d * 144 + tid];
        W[n * 144 + tid] = acc;
    } else if (tid < 208) {
        const int o = tid - 144;
        float acc = 0.f;
#pragma unroll
        for (int d = 0; d < EMB; ++d) acc += e[d] * bp[d * 64 + o];
        biasN[n * 64 + o] = acc;
    } else if (tid < 216) {
        const int o = tid - 208;
        float acc = 0.f;
#pragma unroll
        for (int d = 0; d < EMB; ++d) acc += e[d] * wwsp[d * 8 + o];
        wws[n * 8 + o] = acc;
    } else if (tid < 224) {
        const int o = tid - 216;
        float acc = 0.f;
#pragma unroll
        for (int d = 0; d < EMB; ++d) acc += e[d] * wwtp[d * 8 + o];
        wwt[n * 8 + o] = acc;
    }
}

// ---------------- K5: M[b,n] = mean_f xws, wsum[b,n] = sum_t xw[b,t,n]*T[t] ----------------
__global__ __launch_bounds__(128) void k_Mwsum(const float* __restrict__ xwin,
                                               const float* __restrict__ S,
                                               const int* __restrict__ bidx,
                                               const int* __restrict__ jumpc,
                                               const float* __restrict__ Tp,
                                               float* __restrict__ M,
                                               float* __restrict__ wsum) {
    const int b = blockIdx.y;
    const int n0 = blockIdx.x * 125;
    const int tid = threadIdx.x;
    __shared__ float xsf[NN];
    __shared__ float Tl[TT];
    const int t0 = bidx[0], t1 = bidx[1], t2 = bidx[2];
    if (tid < TT) Tl[tid] = Tp[tid];
    const float* xb = xwin + (size_t)b * TT * NN;
    for (int m = tid; m < NN; m += 128)
        xsf[m] = xb[t0 * NN + m] + xb[t1 * NN + m] + xb[t2 * NN + m];
    __syncthreads();
    if (tid < 125) {
        const int n = n0 + tid;
        float ws_ = 0.f;
#pragma unroll
        for (int t = 0; t < TT; ++t) ws_ += xb[t * NN + n] * Tl[t];
        const float jc = (float)jumpc[0];
        const float jterm = jc * (2.f * xb[t0 * NN + n] + xb[t1 * NN + n]);
        float acc = 0.f;
        for (int m = 0; m < NN; ++m) acc += xsf[m] * S[m * NN + n];
        M[b * NN + n] = (acc + jterm) * (1.f / 3.f);
        wsum[b * NN + n] = ws_;
    }
}

// ---------------- K_wpackB: weights -> MFMA B-fragments, bf16 ----------------
// wq[shift s=kh*3+kw][lane][j]: B[k=(lane>>5)*8+j][n=lane&31], n<8 real, else 0.
__global__ __launch_bounds__(256) void k_wpackB(const float* __restrict__ wm,
                                                const float* __restrict__ wx,
                                                unsigned short* __restrict__ wq) {
    const int i = blockIdx.x * 256 + threadIdx.x;
    if (i >= 9 * 64 * 8) return;
    const int j = i & 7;
    const int rest = i >> 3;
    const int lane = rest & 63;
    const int s = rest >> 6;           // 0..8
    const int kh = s / 3, kw = s - kh * 3;
    const int n = lane & 31;
    const int t = (lane >> 5) * 8 + j;
    float v = 0.f;
    if (t < TT) {
        if (n < 4) v = wm[((n * TT + t) * 3 + kh) * 3 + kw];
        else if (n < 8) v = wx[(((n - 4) * TT + t) * 3 + kh) * 3 + kw];
    }
    wq[i] = f2bf(v);
}

// ---------------- K6: fused dual conv via MFMA (bf16), [col][t] LDS, ring of 4 rows --------
// Grid (32, BB): blockIdx.x -> cb = x>>3 (col-block of 128), rb = x&7 (row band of 63).
// Block: 4 waves; wave w owns the 32-col tile at C0 + w*32. Staged cols C0-1 .. C0+130.
// LDS row layout: [sc 0..131][24 bf16 t-slots] (48B/col stride -> conflict-free b128 reads).
#define SLOTW 132
#define SLOTS (SLOTW * 24)            // ushorts per row slot (3168)

__global__ __launch_bounds__(256, 2) void k_conv(const float* __restrict__ MPG,
                                                 const unsigned short* __restrict__ wq,
                                                 const float* __restrict__ bmv,
                                                 const float* __restrict__ bxv,
                                                 float* __restrict__ partials) {
    const int b = blockIdx.y;
    const int cb = blockIdx.x >> 3;
    const int rb = blockIdx.x & 7;
    const int C0 = cb * 128;
    const int R0 = rb * 63;
    const int R1 = (R0 + 62 < NN - 1) ? R0 + 62 : NN - 1;
    const int tid = threadIdx.x;
    const int w = __builtin_amdgcn_readfirstlane(tid >> 6);
    const int lane = tid & 63;
    const int hi = lane >> 5;

    __shared__ unsigned short lsd[4 * SLOTS];
    __shared__ float wred[4][8][2];

    const float* basef = MPG + (size_t)b * TT * NN * NN;

    // ---- load B fragments (weights) ----
    bf16x8 bfq[9];
#pragma unroll
    for (int s = 0; s < 9; ++s)
        bfq[s] = *reinterpret_cast<const bf16x8*>(wq + (s * 64 + lane) * 8);

    // ---- staging precompute: f = tid + k*256 over 12 t-planes x 132 cols ----
    int loff[7];
    size_t goff[7];
    bool okf[7], okc[7];
#pragma unroll
    for (int k = 0; k < 7; ++k) {
        const int f = tid + k * 256;
        okf[k] = (f < TT * SLOTW);
        const int t = f / SLOTW;
        const int sc = f - t * SLOTW;
        const int gcol = C0 - 1 + sc;
        okc[k] = okf[k] && (gcol >= 0) && (gcol < NN);
        goff[k] = (size_t)t * (NN * NN) + (okc[k] ? gcol : 0);
        loff[k] = sc * 24 + t;
    }

    // ---- zero the t=12..15 pad in all 4 slots (read as K 12..15) ----
    for (int z = tid; z < 4 * SLOTW * 4; z += 256) {
        const int s = z / (SLOTW * 4);
        const int r2 = z - s * (SLOTW * 4);
        const int sc = r2 >> 2;
        lsd[s * SLOTS + sc * 24 + 12 + (r2 & 3)] = 0;
    }

    // ---- per-lane constants ----
    const int ch = lane & 31;
    const float biasv = (ch < 4) ? bmv[ch] : ((ch < 8) ? bxv[ch - 4] : 0.f);
    float mkv[16];
#pragma unroll
    for (int i = 0; i < 16; ++i) {
        const int p = C0 + w * 32 + (i & 3) + 8 * (i >> 2) + 4 * hi;
        mkv[i] = (p < NN) ? 1.f : 0.f;
    }
    const int aoff = (w * 32 + (lane & 31)) * 48 + hi * 16;   // bytes within slot

    // ---- prologue: stage rows R0-1, R0, R0+1 into slots (row+1)&3 ----
#pragma unroll
    for (int q = 0; q < 3; ++q) {
        const int rr = R0 - 1 + q;
        const bool rowok = (rr >= 0);   // rr < NN guaranteed here
        float sv[7];
#pragma unroll
        for (int k = 0; k < 7; ++k)
            sv[k] = (rowok && okc[k]) ? basef[goff[k] + (size_t)rr * NN] : 0.f;
        unsigned short* dst = lsd + ((rr + 1) & 3) * SLOTS;
#pragma unroll
        for (int k = 0; k < 7; ++k)
            if (okf[k]) dst[loff[k]] = f2bf(sv[k]);
    }
    __syncthreads();

    float sumv = 0.f, maxv = 0.f;

    for (int r = R0; r <= R1; ++r) {
        // issue next-row staging loads early (T14)
        const int rr = r + 2;
        const bool do_stage = (rr <= R1 + 1);
        float sv[7];
        if (do_stage) {
            const bool rowok = (rr < NN);
#pragma unroll
            for (int k = 0; k < 7; ++k)
                sv[k] = (rowok && okc[k]) ? basef[goff[k] + (size_t)rr * NN] : 0.f;
        }

        // compute: 9 shifts accumulate into one 32x32 C tile
        f32x16 acc;
#pragma unroll
        for (int i = 0; i < 16; ++i) acc[i] = biasv;
#pragma unroll
        for (int kh = 0; kh < 3; ++kh) {
            const char* sb = reinterpret_cast<const char*>(lsd + ((r + kh) & 3) * SLOTS);
#pragma unroll
            for (int kw = 0; kw < 3; ++kw) {
                const bf16x8 a = *reinterpret_cast<const bf16x8*>(sb + aoff + kw * 48);
                acc = __builtin_amdgcn_mfma_f32_32x32x16_bf16(a, bfq[kh * 3 + kw], acc, 0, 0, 0);
            }
        }
        // relu + masked running mean-sum / max
#pragma unroll
        for (int i = 0; i < 16; ++i) {
            const float v = fmaxf(acc[i], 0.f) * mkv[i];
            sumv += v;
            maxv = fmaxf(maxv, v);
        }

        // write staged row, one barrier per row
        if (do_stage) {
            unsigned short* dst = lsd + ((rr + 1) & 3) * SLOTS;
#pragma unroll
            for (int k = 0; k < 7; ++k)
                if (okf[k]) dst[loff[k]] = f2bf(sv[k]);
        }
        __syncthreads();
    }

    // ---- reduce: lane l and l^32 share channel ch = l&31 ----
    sumv += __shfl_xor(sumv, 32, 64);
    maxv = fmaxf(maxv, __shfl_xor(maxv, 32, 64));
    if (lane < 8) {
        wred[w][lane][0] = sumv;
        wred[w][lane][1] = maxv;
    }
    __syncthreads();
    if (tid < 8) {
        const float s = wred[0][tid][0] + wred[1][tid][0] + wred[2][tid][0] + wred[3][tid][0];
        const float mx = fmaxf(fmaxf(wred[0][tid][1], wred[1][tid][1]),
                               fmaxf(wred[2][tid][1], wred[3][tid][1]));
        partials[((size_t)b * 32 + blockIdx.x) * 8 + tid] = (tid < 4) ? s : mx;
    }
}

// ---------------- K7: reduce partials[b][32][8] -> topo[b][8] ----------------
__global__ __launch_bounds__(256) void k_topo(const float* __restrict__ partials,
                                              float* __restrict__ topo) {
    const int b = blockIdx.x;
    const int tid = threadIdx.x;
    const int c = tid & 7;
    const int g = tid >> 3;  // 32 groups -> one partial each
    float vs = 0.f, vm = 0.f;
    if (g < 32) {
        const float v = partials[((size_t)b * 32 + g) * 8 + c];
        vs = v;
        vm = v;
    }
    __shared__ float red[256];
    red[tid] = (c < 4) ? vs : vm;
    __syncthreads();
    for (int s = 16; s > 0; s >>= 1) {
        if (g < s) {
            const float a = red[tid];
            const float bv = red[tid + s * 8];
            red[tid] = (c < 4) ? (a + bv) : fmaxf(a, bv);
        }
        __syncthreads();
    }
    if (tid < 8) topo[b * 8 + tid] = (tid < 4) ? red[tid] * (1.f / (NN * (float)NN)) : red[tid];
}

// ---------------- K8: assemble output ----------------
__global__ __launch_bounds__(64) void k_out(const float* __restrict__ x,
                                            const float* __restrict__ y1,
                                            const float* __restrict__ y2,
                                            const float* __restrict__ W,
                                            const float* __restrict__ biasN,
                                            const float* __restrict__ wws,
                                            const float* __restrict__ wwt,
                                            const float* __restrict__ M,
                                            const float* __restrict__ wsum,
                                            const float* __restrict__ topo,
                                            float* __restrict__ out) {
    const int bn = blockIdx.x;
    const int b = bn / NN;
    const int n = bn - b * NN;
    const int o = threadIdx.x;
    float val;
    if (o < 48) {
        val = x[bn] * W[n * 144 + o] + y1[bn] * W[n * 144 + 48 + o] + y2[bn] * W[n * 144 + 96 + o];
    } else if (o < 56) {
        const int oo = o - 48;
        val = M[bn] * wws[n * 8 + oo] * topo[b * 8 + oo];
    } else {
        const int oo = o - 56;
        val = wsum[bn] * wwt[n * 8 + oo];
    }
    out[(size_t)bn * 64 + o] = val + biasN[n * 64 + o];
}

extern "C" void kernel_launch(void* const* d_in, const int* in_sizes, int n_in,
                              void* d_out, int out_size, void* d_ws, size_t ws_size,
                              hipStream_t stream) {
    const float* x    = (const float*)d_in[0];
    const float* xw   = (const float*)d_in[1];
    const float* E    = (const float*)d_in[2];
    const float* MPG  = (const float*)d_in[4];
    const int*   bidx = (const int*)d_in[5];
    const int*   stay = (const int*)d_in[7];
    const int*   jump = (const int*)d_in[8];
    const float* wp   = (const float*)d_in[9];
    const float* wwsp = (const float*)d_in[10];
    const float* wwtp = (const float*)d_in[11];
    const float* bp   = (const float*)d_in[12];
    const float* Tp   = (const float*)d_in[13];
    const float* cmw  = (const float*)d_in[14];
    const float* cmb  = (const float*)d_in[15];
    const float* cxw  = (const float*)d_in[16];
    const float* cxb  = (const float*)d_in[17];
    float* out = (float*)d_out;

    float* w = (float*)d_ws;
    float* S     = w;               // 250000
    float* y1    = S + 250000;      // 16000
    float* y2    = y1 + 16000;      // 16000
    float* W     = y2 + 16000;      // 72000
    float* biasN = W + 72000;       // 32000
    float* wws   = biasN + 32000;   // 4000
    float* wwt   = wws + 4000;      // 4000
    float* M     = wwt + 4000;      // 16000
    float* wsum  = M + 16000;       // 16000
    float* parts = wsum + 16000;    // 8192 (32 b x 32 blk x 8)
    float* topo  = parts + 8192;    // 256
    float* wpckf = topo + 256;      // 2304 floats = 4608 ushorts B-fragments
    unsigned short* wq = (unsigned short*)wpckf;

    k_wpackB<<<18, 256, 0, stream>>>(cmw, cxw, wq);
    k_softmaxS<<<NN, 256, 0, stream>>>(E, stay, S);
    k_matvecS<<<dim3(125, BB), 256, 0, stream>>>(S, x, y1);
    k_matvecS<<<dim3(125, BB), 256, 0, stream>>>(S, y1, y2);
    k_smallpre<<<NN, 256, 0, stream>>>(E, wp, bp, wwsp, wwtp, W, biasN, wws, wwt);
    k_Mwsum<<<dim3(4, BB), 128, 0, stream>>>(xw, S, bidx, jump, Tp, M, wsum);
    k_conv<<<dim3(32, BB), 256, 0, stream>>>(MPG, wq, cmb, cxb, parts);
    k_topo<<<BB, 256, 0, stream>>>(parts, topo);
    k_out<<<BB * NN, 64, 0, stream>>>(x, y1, y2, W, biasN, wws, wwt, M, wsum, topo, out);
}